// Round 3
// baseline (365.106 us; speedup 1.0000x reference)
//
#include <hip/hip_runtime.h>

typedef __bf16 bf16x8 __attribute__((ext_vector_type(8)));
typedef float  f32x4  __attribute__((ext_vector_type(4)));

constexpr int BM = 128, BN = 128, BK = 32;
constexpr int MDIM = 65536, NDIM = 1152, KDIM = 768;
constexpr int NBN = NDIM / BN;          // 9
constexpr int NKT = KDIM / BK;          // 24
constexpr int GRID = (MDIM / BM) * NBN; // 4608 (divisible by 8 -> bijective XCD swizzle)
constexpr int LDSROWB = BK * 2;

// fragment-major ws layout: for 16-row block R, K-step kt, lane l (l>>4=kg, l&15=fr):
//   16B chunk = rows[R*16 + fr], cols[kt*32 + kg*8 .. +8)  as bf16
// flat chunk index c = (R*24 + kt)*64 + l ; element offset = c*8
constexpr int RSTRIDE = NKT * 64 * 8;   // 12288 bf16 elems per 16-row block

__device__ __forceinline__ unsigned pk2(float x, float y) {
  __bf16 a = (__bf16)x, b = (__bf16)y;
  return (unsigned)__builtin_bit_cast(unsigned short, a) |
         ((unsigned)__builtin_bit_cast(unsigned short, b) << 16);
}

// ---------------- shared epilogue: bias + bilinear pos-emb + store ----------------
__device__ __forceinline__ void epilogue(const f32x4 acc[4][4], int bm, int bn,
                                         int wr, int wc, int lane,
                                         const int* __restrict__ ss,
                                         const float* __restrict__ bias,
                                         const float* __restrict__ pos,
                                         float* __restrict__ out) {
  const int fr = lane & 15;
  const int kg = lane >> 4;
  const int colbase = bn * BN + wc * 64 + fr;
  float bvals[4];
#pragma unroll
  for (int nf = 0; nf < 4; ++nf) bvals[nf] = bias[colbase + nf * 16];

  const int s  = bm >> 3;
  const int h  = ss[2 * s];
  const int w  = ss[2 * s + 1];
  const int hw = h * w;
  const float rh = 16.0f / (float)h;
  const float rw = 16.0f / (float)w;

  const int row0 = bm * BM + wr * 64 + kg * 4;

#pragma unroll
  for (int mf = 0; mf < 4; ++mf) {
#pragma unroll
    for (int rg = 0; rg < 4; ++rg) {
      const int row = row0 + mf * 16 + rg;
      int p = row & 1023;
      if (p >= hw) p = 0;
      const int y = p / w;
      const int x = p - y * w;
      const float fy = ((float)y + 0.5f) * rh - 0.5f;
      const float fx = ((float)x + 0.5f) * rw - 0.5f;
      const float yf = floorf(fy), xf = floorf(fx);
      const float ty = fy - yf,   tx = fx - xf;
      int iy0 = (int)yf, ix0 = (int)xf;
      int iy1 = iy0 + 1 > 15 ? 15 : iy0 + 1;
      int ix1 = ix0 + 1 > 15 ? 15 : ix0 + 1;
      iy0 = iy0 < 0 ? 0 : iy0;
      ix0 = ix0 < 0 ? 0 : ix0;
      const float* g00 = pos + (size_t)(iy0 * 16 + ix0) * NDIM;
      const float* g01 = pos + (size_t)(iy0 * 16 + ix1) * NDIM;
      const float* g10 = pos + (size_t)(iy1 * 16 + ix0) * NDIM;
      const float* g11 = pos + (size_t)(iy1 * 16 + ix1) * NDIM;
      float* orow = out + (size_t)row * NDIM;
#pragma unroll
      for (int nf = 0; nf < 4; ++nf) {
        const int col = colbase + nf * 16;
        const float p00 = g00[col], p01 = g01[col];
        const float p10 = g10[col], p11 = g11[col];
        const float top = p00 + tx * (p01 - p00);
        const float bot = p10 + tx * (p11 - p10);
        const float pv  = top + ty * (bot - top);
        orow[col] = acc[mf][nf][rg] + bvals[nf] + pv;
      }
    }
  }
}

// ---------------- fp32 -> bf16 fragment-major repack ----------------
// one thread per 16B output chunk; grid covers exactly nChunks/256 blocks
__global__ __launch_bounds__(256)
void cvt_frag_kernel(const float* __restrict__ in, __bf16* __restrict__ out) {
  const int c   = blockIdx.x * 256 + threadIdx.x;
  const int fr  = c & 15;
  const int kg  = (c >> 4) & 3;
  const int ktR = c >> 6;
  const int kt  = ktR % NKT;
  const int R   = ktR / NKT;
  const float* src = in + (size_t)(R * 16 + fr) * KDIM + kt * 32 + kg * 8;
  const float4 a = *reinterpret_cast<const float4*>(src);
  const float4 b = *reinterpret_cast<const float4*>(src + 4);
  bf16x8 r;
  r[0] = (__bf16)a.x; r[1] = (__bf16)a.y; r[2] = (__bf16)a.z; r[3] = (__bf16)a.w;
  r[4] = (__bf16)b.x; r[5] = (__bf16)b.y; r[6] = (__bf16)b.z; r[7] = (__bf16)b.w;
  *reinterpret_cast<bf16x8*>(out + (size_t)c * 8) = r;
}

// ---------------- main GEMM: direct global->register fragments, no LDS, no barriers ----
__global__ __launch_bounds__(256, 2)
void gemm_frag_kernel(const __bf16* __restrict__ Aw,   // fragment-major A
                      const __bf16* __restrict__ Bw,   // fragment-major W
                      const int*   __restrict__ ss,
                      const float* __restrict__ bias,
                      const float* __restrict__ pos,
                      float* __restrict__ out) {
  const int tid  = threadIdx.x;
  const int lane = tid & 63;
  const int wid  = tid >> 6;
  const int wr   = wid >> 1;
  const int wc   = wid & 1;

  const int bidh = blockIdx.x;
  const int bid  = (bidh & 7) * (GRID / 8) + (bidh >> 3);
  const int bm   = bid / NBN;
  const int bn   = bid % NBN;

  const __bf16* pA = Aw + (size_t)(bm * 8 + wr * 4) * RSTRIDE + lane * 8;
  const __bf16* pB = Bw + (size_t)(bn * 8 + wc * 4) * RSTRIDE + lane * 8;

  f32x4 acc[4][4];
#pragma unroll
  for (int i = 0; i < 4; ++i)
#pragma unroll
    for (int j = 0; j < 4; ++j) acc[i][j] = (f32x4)0.0f;

  bf16x8 a0[4], b0[4], a1[4], b1[4];

  auto lda = [&](bf16x8* d, int kt) {
#pragma unroll
    for (int mf = 0; mf < 4; ++mf)
      d[mf] = *reinterpret_cast<const bf16x8*>(pA + mf * RSTRIDE + kt * 512);
  };
  auto ldb = [&](bf16x8* d, int kt) {
#pragma unroll
    for (int nf = 0; nf < 4; ++nf)
      d[nf] = *reinterpret_cast<const bf16x8*>(pB + nf * RSTRIDE + kt * 512);
  };
  auto mm = [&](const bf16x8* a, const bf16x8* b) {
#pragma unroll
    for (int mf = 0; mf < 4; ++mf)
#pragma unroll
      for (int nf = 0; nf < 4; ++nf)
        acc[mf][nf] = __builtin_amdgcn_mfma_f32_16x16x32_bf16(a[mf], b[nf], acc[mf][nf], 0, 0, 0);
  };

  lda(a0, 0); ldb(b0, 0);
#pragma unroll
  for (int kt = 0; kt < NKT; kt += 2) {
    lda(a1, kt + 1); ldb(b1, kt + 1);     // prefetch flies under MFMA
    mm(a0, b0);
    if (kt + 2 < NKT) { lda(a0, kt + 2); ldb(b0, kt + 2); }
    mm(a1, b1);
  }

  epilogue(acc, bm, bn, wr, wc, lane, ss, bias, pos, out);
}

// ---------------- fallback: fp32 inputs, reg-stage + on-the-fly convert (R0, passed) ----
__global__ __launch_bounds__(256, 2)
void gemm_fb_kernel(const float* __restrict__ A,
                    const int*   __restrict__ ss,
                    const float* __restrict__ Wm,
                    const float* __restrict__ bias,
                    const float* __restrict__ pos,
                    float* __restrict__ out) {
  __shared__ unsigned short As[2][BM * BK];
  __shared__ unsigned short Bs[2][BM * BK];

  const int tid  = threadIdx.x;
  const int lane = tid & 63;
  const int wid  = tid >> 6;
  const int wr   = wid >> 1;
  const int wc   = wid & 1;

  const int bidh = blockIdx.x;
  const int bid  = (bidh & 7) * (GRID / 8) + (bidh >> 3);
  const int bm   = bid / NBN;
  const int bn   = bid % NBN;

  const int srow0 = tid >> 3;
  const int skc   = tid & 7;
  const float* Ag = A  + (size_t)(bm * BM + srow0) * KDIM + skc * 4;
  const float* Bg = Wm + (size_t)(bn * BN + srow0) * KDIM + skc * 4;

  float4 ra[4], rb[4];

  auto stage_load = [&](int kt) {
    const int ko = kt * BK;
#pragma unroll
    for (int r = 0; r < 4; ++r) {
      ra[r] = *reinterpret_cast<const float4*>(Ag + (size_t)(r * 32) * KDIM + ko);
      rb[r] = *reinterpret_cast<const float4*>(Bg + (size_t)(r * 32) * KDIM + ko);
    }
  };

  auto stage_write = [&](int buf) {
#pragma unroll
    for (int r = 0; r < 4; ++r) {
      const int arow = r * 32 + srow0;
      int off = arow * LDSROWB + skc * 8;
      off ^= (arow & 7) << 4;
      uint2 pa, pb;
      pa.x = pk2(ra[r].x, ra[r].y); pa.y = pk2(ra[r].z, ra[r].w);
      pb.x = pk2(rb[r].x, rb[r].y); pb.y = pk2(rb[r].z, rb[r].w);
      *reinterpret_cast<uint2*>(reinterpret_cast<char*>(&As[buf][0]) + off) = pa;
      *reinterpret_cast<uint2*>(reinterpret_cast<char*>(&Bs[buf][0]) + off) = pb;
    }
  };

  f32x4 acc[4][4];
#pragma unroll
  for (int i = 0; i < 4; ++i)
#pragma unroll
    for (int j = 0; j < 4; ++j) acc[i][j] = (f32x4)0.0f;

  const int fr = lane & 15;
  const int kg = lane >> 4;
  int abase = (wr * 64 + fr) * LDSROWB + kg * 16; abase ^= (fr & 7) << 4;
  int bbase = (wc * 64 + fr) * LDSROWB + kg * 16; bbase ^= (fr & 7) << 4;

  auto compute = [&](int buf) {
    const char* pa = reinterpret_cast<const char*>(&As[buf][0]);
    const char* pb = reinterpret_cast<const char*>(&Bs[buf][0]);
    bf16x8 af[4], bfv[4];
#pragma unroll
    for (int mf = 0; mf < 4; ++mf)
      af[mf] = *reinterpret_cast<const bf16x8*>(pa + abase + mf * 16 * LDSROWB);
#pragma unroll
    for (int nf = 0; nf < 4; ++nf)
      bfv[nf] = *reinterpret_cast<const bf16x8*>(pb + bbase + nf * 16 * LDSROWB);
#pragma unroll
    for (int mf = 0; mf < 4; ++mf)
#pragma unroll
      for (int nf = 0; nf < 4; ++nf)
        acc[mf][nf] = __builtin_amdgcn_mfma_f32_16x16x32_bf16(af[mf], bfv[nf], acc[mf][nf], 0, 0, 0);
  };

  stage_load(0);
  stage_write(0);
  for (int kt = 0; kt < NKT; ++kt) {
    const int cur = kt & 1;
    if (kt + 1 < NKT) stage_load(kt + 1);
    __syncthreads();
    compute(cur);
    if (kt + 1 < NKT) stage_write(cur ^ 1);
  }

  epilogue(acc, bm, bn, wr, wc, lane, ss, bias, pos, out);
}

extern "C" void kernel_launch(void* const* d_in, const int* in_sizes, int n_in,
                              void* d_out, int out_size, void* d_ws, size_t ws_size,
                              hipStream_t stream) {
  const float* A    = (const float*)d_in[0];
  const int*   ss   = (const int*)d_in[1];
  const float* Wm   = (const float*)d_in[2];
  const float* bias = (const float*)d_in[3];
  const float* pos  = (const float*)d_in[4];
  float* out = (float*)d_out;

  const size_t needA = (size_t)MDIM * KDIM * 2;  // 100,663,296 B
  const size_t needW = (size_t)NDIM * KDIM * 2;  //   1,769,472 B

  if (ws_size >= needA + needW) {
    __bf16* Ab = (__bf16*)d_ws;
    __bf16* Bb = (__bf16*)((char*)d_ws + needA);
    const int chunksA = MDIM / 16 * NKT * 64;    // 6,291,456
    const int chunksW = NDIM / 16 * NKT * 64;    //   110,592
    cvt_frag_kernel<<<chunksA / 256, 256, 0, stream>>>(A, Ab);
    cvt_frag_kernel<<<chunksW / 256, 256, 0, stream>>>(Wm, Bb);
    gemm_frag_kernel<<<GRID, 256, 0, stream>>>(Ab, Bb, ss, bias, pos, out);
  } else {
    gemm_fb_kernel<<<GRID, 256, 0, stream>>>(A, ss, Wm, bias, pos, out);
  }
}

// Round 4
// 283.773 us; speedup vs baseline: 1.2866x; 1.2866x over previous
//
#include <hip/hip_runtime.h>

typedef __bf16 bf16x8 __attribute__((ext_vector_type(8)));
typedef float  f32x4  __attribute__((ext_vector_type(4)));

constexpr int BM = 128, BN = 128, BK = 32;
constexpr int MDIM = 65536, NDIM = 1152, KDIM = 768;
constexpr int NBN = NDIM / BN;          // 9
constexpr int NKT = KDIM / BK;          // 24
constexpr int GRID = (MDIM / BM) * NBN; // 4608 (divisible by 8 -> bijective XCD swizzle)
constexpr int LDSROWB = BK * 2;         // 64 B per tile row (32 bf16)

// ws holds "LDS images": per (panel, kt) an 8 KB block that is byte-for-byte the
// desired (XOR-swizzled) LDS tile. Staging is then a linear contiguous copy
// (global_load_lds-compatible), and swizzled ds_reads are bank-conflict-free.
// Swizzle: addr = (r*64 + p*16) ^ ((r&7)<<4)   [bijective: triangular XOR on bits 4-6]

__device__ __forceinline__ void gload16(const void* g, void* l) {
  __builtin_amdgcn_global_load_lds(
      (const __attribute__((address_space(1))) void*)g,
      (__attribute__((address_space(3))) void*)l, 16, 0, 0);
}

__device__ __forceinline__ unsigned pk2(float x, float y) {
  __bf16 a = (__bf16)x, b = (__bf16)y;
  return (unsigned)__builtin_bit_cast(unsigned short, a) |
         ((unsigned)__builtin_bit_cast(unsigned short, b) << 16);
}

// ---------------- shared epilogue: bias + bilinear pos-emb + store ----------------
__device__ __forceinline__ void epilogue(const f32x4 acc[4][4], int bm, int bn,
                                         int wr, int wc, int lane,
                                         const int* __restrict__ ss,
                                         const float* __restrict__ bias,
                                         const float* __restrict__ pos,
                                         float* __restrict__ out) {
  const int fr = lane & 15;
  const int kg = lane >> 4;
  const int colbase = bn * BN + wc * 64 + fr;
  float bvals[4];
#pragma unroll
  for (int nf = 0; nf < 4; ++nf) bvals[nf] = bias[colbase + nf * 16];

  const int s  = bm >> 3;
  const int h  = ss[2 * s];
  const int w  = ss[2 * s + 1];
  const int hw = h * w;
  const float rh = 16.0f / (float)h;
  const float rw = 16.0f / (float)w;

  const int row0 = bm * BM + wr * 64 + kg * 4;

#pragma unroll
  for (int mf = 0; mf < 4; ++mf) {
#pragma unroll
    for (int rg = 0; rg < 4; ++rg) {
      const int row = row0 + mf * 16 + rg;
      int p = row & 1023;
      if (p >= hw) p = 0;          // padded region replicates resized[0] == grid[0,0]
      const int y = p / w;
      const int x = p - y * w;
      const float fy = ((float)y + 0.5f) * rh - 0.5f;
      const float fx = ((float)x + 0.5f) * rw - 0.5f;
      const float yf = floorf(fy), xf = floorf(fx);
      const float ty = fy - yf,   tx = fx - xf;
      int iy0 = (int)yf, ix0 = (int)xf;
      int iy1 = iy0 + 1 > 15 ? 15 : iy0 + 1;
      int ix1 = ix0 + 1 > 15 ? 15 : ix0 + 1;
      iy0 = iy0 < 0 ? 0 : iy0;
      ix0 = ix0 < 0 ? 0 : ix0;
      const float* g00 = pos + (size_t)(iy0 * 16 + ix0) * NDIM;
      const float* g01 = pos + (size_t)(iy0 * 16 + ix1) * NDIM;
      const float* g10 = pos + (size_t)(iy1 * 16 + ix0) * NDIM;
      const float* g11 = pos + (size_t)(iy1 * 16 + ix1) * NDIM;
      float* orow = out + (size_t)row * NDIM;
#pragma unroll
      for (int nf = 0; nf < 4; ++nf) {
        const int col = colbase + nf * 16;
        const float p00 = g00[col], p01 = g01[col];
        const float p10 = g10[col], p11 = g11[col];
        const float top = p00 + tx * (p01 - p00);
        const float bot = p10 + tx * (p11 - p10);
        const float pv  = top + ty * (bot - top);
        orow[col] = acc[mf][nf][rg] + bvals[nf] + pv;
      }
    }
  }
}

// ---------------- fp32 -> bf16 swizzled-LDS-image repack ----------------
// One thread per 16B output chunk. Output perfectly coalesced; input reads are
// contiguous 128B per 4-thread group (permuted within), fully cache-friendly.
__global__ __launch_bounds__(256)
void repack_kernel(const float* __restrict__ in, __bf16* __restrict__ out) {
  const int c    = blockIdx.x * 256 + threadIdx.x;
  const int c_in = c & 511;        // chunk within 8KB image
  const int img  = c >> 9;
  const int kt   = img % NKT;
  const int pan  = img / NKT;      // 128-row panel index
  const int o = c_in * 16;         // swizzled (physical) offset
  const int u = (o >> 6) & 7;
  const int a = o ^ ((u ^ (u >> 2)) << 4);   // invert triangular XOR -> logical addr
  const int r = a >> 6;            // tile row 0..127
  const int p = (a >> 4) & 3;      // 16B part within row
  const float* src = in + (size_t)(pan * 128 + r) * KDIM + kt * 32 + p * 8;
  const float4 x = *reinterpret_cast<const float4*>(src);
  const float4 y = *reinterpret_cast<const float4*>(src + 4);
  uint2 v0, v1;
  v0.x = pk2(x.x, x.y); v0.y = pk2(x.z, x.w);
  v1.x = pk2(y.x, y.y); v1.y = pk2(y.z, y.w);
  uint4 r4; r4.x = v0.x; r4.y = v0.y; r4.z = v1.x; r4.w = v1.y;
  *reinterpret_cast<uint4*>(out + (size_t)c * 8) = r4;
}

// ---------------- main GEMM: global_load_lds staging of pre-swizzled images ----------
__global__ __launch_bounds__(256, 3)
void gemm_swz_kernel(const __bf16* __restrict__ Aimg,  // [512][24][8KB] swizzled images
                     const __bf16* __restrict__ Bimg,  // [9][24][8KB]
                     const int*   __restrict__ ss,
                     const float* __restrict__ bias,
                     const float* __restrict__ pos,
                     float* __restrict__ out) {
  __shared__ __bf16 As[2][BM * BK];
  __shared__ __bf16 Bs[2][BM * BK];

  const int tid  = threadIdx.x;
  const int lane = tid & 63;
  const int wid  = tid >> 6;
  const int wr   = wid >> 1;
  const int wc   = wid & 1;

  const int bidh = blockIdx.x;
  const int bid  = (bidh & 7) * (GRID / 8) + (bidh >> 3);
  const int bm   = bid / NBN;
  const int bn   = bid % NBN;

  auto stage = [&](int kt, int buf) {
    const __bf16* wsA = Aimg + ((size_t)(bm * NKT + kt) << 12);  // 4096 bf16 / image
    const __bf16* wsB = Bimg + ((size_t)(bn * NKT + kt) << 12);
    gload16(wsA + tid * 8,         (char*)(&As[buf][0]) + tid * 16);
    gload16(wsA + (256 + tid) * 8, (char*)(&As[buf][0]) + (256 + tid) * 16);
    gload16(wsB + tid * 8,         (char*)(&Bs[buf][0]) + tid * 16);
    gload16(wsB + (256 + tid) * 8, (char*)(&Bs[buf][0]) + (256 + tid) * 16);
  };

  f32x4 acc[4][4];
#pragma unroll
  for (int i = 0; i < 4; ++i)
#pragma unroll
    for (int j = 0; j < 4; ++j) acc[i][j] = (f32x4)0.0f;

  const int fr = lane & 15;
  const int kg = lane >> 4;
  // full row = wX*64 + mf*16 + fr; (row&7)==(fr&7); mf offset (mf*1024B) is
  // above the XOR bits, so swizzle folds into the lane-constant base.
  const int abase = (((wr * 64 + fr) * LDSROWB) + kg * 16) ^ ((fr & 7) << 4);
  const int bbase = (((wc * 64 + fr) * LDSROWB) + kg * 16) ^ ((fr & 7) << 4);

  auto compute = [&](int buf) {
    const char* pa = reinterpret_cast<const char*>(&As[buf][0]);
    const char* pb = reinterpret_cast<const char*>(&Bs[buf][0]);
    bf16x8 af[4], bfv[4];
#pragma unroll
    for (int mf = 0; mf < 4; ++mf)
      af[mf] = *reinterpret_cast<const bf16x8*>(pa + abase + mf * 16 * LDSROWB);
#pragma unroll
    for (int nf = 0; nf < 4; ++nf)
      bfv[nf] = *reinterpret_cast<const bf16x8*>(pb + bbase + nf * 16 * LDSROWB);
#pragma unroll
    for (int mf = 0; mf < 4; ++mf)
#pragma unroll
      for (int nf = 0; nf < 4; ++nf)
        acc[mf][nf] = __builtin_amdgcn_mfma_f32_16x16x32_bf16(af[mf], bfv[nf], acc[mf][nf], 0, 0, 0);
  };

  stage(0, 0);
  for (int kt = 0; kt < NKT; ++kt) {
    const int cur = kt & 1;
    __syncthreads();                           // drains stage of buf[cur]
    if (kt + 1 < NKT) stage(kt + 1, cur ^ 1);  // async prefetch flies under MFMA
    compute(cur);
  }

  epilogue(acc, bm, bn, wr, wc, lane, ss, bias, pos, out);
}

// ---------------- fallback: fp32 inputs, reg-stage + on-the-fly convert (known-good) ----
__global__ __launch_bounds__(256, 2)
void gemm_fb_kernel(const float* __restrict__ A,
                    const int*   __restrict__ ss,
                    const float* __restrict__ Wm,
                    const float* __restrict__ bias,
                    const float* __restrict__ pos,
                    float* __restrict__ out) {
  __shared__ unsigned short As[2][BM * BK];
  __shared__ unsigned short Bs[2][BM * BK];

  const int tid  = threadIdx.x;
  const int lane = tid & 63;
  const int wid  = tid >> 6;
  const int wr   = wid >> 1;
  const int wc   = wid & 1;

  const int bidh = blockIdx.x;
  const int bid  = (bidh & 7) * (GRID / 8) + (bidh >> 3);
  const int bm   = bid / NBN;
  const int bn   = bid % NBN;

  const int srow0 = tid >> 3;
  const int skc   = tid & 7;
  const float* Ag = A  + (size_t)(bm * BM + srow0) * KDIM + skc * 4;
  const float* Bg = Wm + (size_t)(bn * BN + srow0) * KDIM + skc * 4;

  float4 ra[4], rb[4];

  auto stage_load = [&](int kt) {
    const int ko = kt * BK;
#pragma unroll
    for (int r = 0; r < 4; ++r) {
      ra[r] = *reinterpret_cast<const float4*>(Ag + (size_t)(r * 32) * KDIM + ko);
      rb[r] = *reinterpret_cast<const float4*>(Bg + (size_t)(r * 32) * KDIM + ko);
    }
  };

  auto stage_write = [&](int buf) {
#pragma unroll
    for (int r = 0; r < 4; ++r) {
      const int arow = r * 32 + srow0;
      int off = arow * LDSROWB + skc * 8;
      off ^= (arow & 7) << 4;
      uint2 pa, pb;
      pa.x = pk2(ra[r].x, ra[r].y); pa.y = pk2(ra[r].z, ra[r].w);
      pb.x = pk2(rb[r].x, rb[r].y); pb.y = pk2(rb[r].z, rb[r].w);
      *reinterpret_cast<uint2*>(reinterpret_cast<char*>(&As[buf][0]) + off) = pa;
      *reinterpret_cast<uint2*>(reinterpret_cast<char*>(&Bs[buf][0]) + off) = pb;
    }
  };

  f32x4 acc[4][4];
#pragma unroll
  for (int i = 0; i < 4; ++i)
#pragma unroll
    for (int j = 0; j < 4; ++j) acc[i][j] = (f32x4)0.0f;

  const int fr = lane & 15;
  const int kg = lane >> 4;
  int abase = (wr * 64 + fr) * LDSROWB + kg * 16; abase ^= (fr & 7) << 4;
  int bbase = (wc * 64 + fr) * LDSROWB + kg * 16; bbase ^= (fr & 7) << 4;

  auto compute = [&](int buf) {
    const char* pa = reinterpret_cast<const char*>(&As[buf][0]);
    const char* pb = reinterpret_cast<const char*>(&Bs[buf][0]);
    bf16x8 af[4], bfv[4];
#pragma unroll
    for (int mf = 0; mf < 4; ++mf)
      af[mf] = *reinterpret_cast<const bf16x8*>(pa + abase + mf * 16 * LDSROWB);
#pragma unroll
    for (int nf = 0; nf < 4; ++nf)
      bfv[nf] = *reinterpret_cast<const bf16x8*>(pb + bbase + nf * 16 * LDSROWB);
#pragma unroll
    for (int mf = 0; mf < 4; ++mf)
#pragma unroll
      for (int nf = 0; nf < 4; ++nf)
        acc[mf][nf] = __builtin_amdgcn_mfma_f32_16x16x32_bf16(af[mf], bfv[nf], acc[mf][nf], 0, 0, 0);
  };

  stage_load(0);
  stage_write(0);
  for (int kt = 0; kt < NKT; ++kt) {
    const int cur = kt & 1;
    if (kt + 1 < NKT) stage_load(kt + 1);
    __syncthreads();
    compute(cur);
    if (kt + 1 < NKT) stage_write(cur ^ 1);
  }

  epilogue(acc, bm, bn, wr, wc, lane, ss, bias, pos, out);
}

extern "C" void kernel_launch(void* const* d_in, const int* in_sizes, int n_in,
                              void* d_out, int out_size, void* d_ws, size_t ws_size,
                              hipStream_t stream) {
  const float* A    = (const float*)d_in[0];
  const int*   ss   = (const int*)d_in[1];
  const float* Wm   = (const float*)d_in[2];
  const float* bias = (const float*)d_in[3];
  const float* pos  = (const float*)d_in[4];
  float* out = (float*)d_out;

  const size_t needA = (size_t)MDIM * KDIM * 2;  // 100,663,296 B
  const size_t needW = (size_t)NDIM * KDIM * 2;  //   1,769,472 B

  if (ws_size >= needA + needW) {
    __bf16* Ab = (__bf16*)d_ws;
    __bf16* Bb = (__bf16*)((char*)d_ws + needA);
    const int chunksA = (MDIM / 16) * NKT * 64;  // 6,291,456 16B chunks
    const int chunksW = (NDIM / 16) * NKT * 64;  //   110,592
    repack_kernel<<<chunksA / 256, 256, 0, stream>>>(A, Ab);
    repack_kernel<<<chunksW / 256, 256, 0, stream>>>(Wm, Bb);
    gemm_swz_kernel<<<GRID, 256, 0, stream>>>(Ab, Bb, ss, bias, pos, out);
  } else {
    gemm_fb_kernel<<<GRID, 256, 0, stream>>>(A, ss, Wm, bias, pos, out);
  }
}